// Round 2
// baseline (925.065 us; speedup 1.0000x reference)
//
#include <hip/hip_runtime.h>
#include <stdint.h>

#define V3 (48*48*48)   // 110592 voxels per channel
#define CIN 32
#define NHID 64
#define BATCH 8

typedef __bf16 bf16x8 __attribute__((ext_vector_type(8)));
typedef float  f32x4  __attribute__((ext_vector_type(4)));

__device__ __forceinline__ unsigned short f2bf(float f) {
  uint32_t u = __float_as_uint(f);
  u += 0x7fffu + ((u >> 16) & 1u);   // round-to-nearest-even
  return (unsigned short)(u >> 16);
}

// ---------------------------------------------------------------- stats ----
__global__ __launch_bounds__(256)
void stats_kernel(const float* __restrict__ x, float* __restrict__ mu,
                  float* __restrict__ rstd) {
  const int bc = blockIdx.x;  // 0..255
  const float4* p = reinterpret_cast<const float4*>(x + (size_t)bc * V3);
  float s = 0.f, s2 = 0.f;
  for (int i = threadIdx.x; i < V3 / 4; i += 256) {
    float4 v = p[i];
    s  += (v.x + v.y) + (v.z + v.w);
    s2 += (v.x * v.x + v.y * v.y) + (v.z * v.z + v.w * v.w);
  }
  for (int o = 32; o; o >>= 1) { s += __shfl_down(s, o); s2 += __shfl_down(s2, o); }
  __shared__ float red[8];
  const int wave = threadIdx.x >> 6, lane = threadIdx.x & 63;
  if (lane == 0) { red[wave] = s; red[4 + wave] = s2; }
  __syncthreads();
  if (threadIdx.x == 0) {
    float S1 = red[0] + red[1] + red[2] + red[3];
    float S2 = red[4] + red[5] + red[6] + red[7];
    float m = S1 / (float)V3;
    float var = S2 / (float)V3 - m * m;
    mu[bc] = m;
    rstd[bc] = rsqrtf(var + 1e-5f);
  }
}

// --------------------------------------------------------------- repack ----
__global__ __launch_bounds__(256)
void repack_kernel(const float* __restrict__ x, unsigned short* __restrict__ xcl) {
  const int bid = blockIdx.x;            // B*48*48 blocks, one (b,d,h) row each
  const int h = bid % 48;
  const int d = (bid / 48) % 48;
  const int b = bid / (48 * 48);
  __shared__ float tile[32][48];
  const float* src = x + (size_t)b * 32 * V3 + (size_t)(d * 48 + h) * 48;
  for (int i = threadIdx.x; i < 32 * 48; i += 256) {
    int c = i / 48, w = i - c * 48;
    tile[c][w] = src[(size_t)c * V3 + w];
  }
  __syncthreads();
  const int i = threadIdx.x;
  if (i < 48 * 4) {
    const int w = i >> 2, pp = i & 3;
    alignas(16) unsigned short pk[8];
#pragma unroll
    for (int j = 0; j < 8; ++j) pk[j] = f2bf(tile[pp * 8 + j][w]);
    *reinterpret_cast<uint4*>(
        &xcl[((size_t)b * V3 + (size_t)(d * 48 + h) * 48 + w) * CIN + pp * 8]) =
        *reinterpret_cast<const uint4*>(pk);
  }
}

// ---------------------------------------------------------------- wprep ----
__global__ __launch_bounds__(256)
void wprep_kernel(const int* __restrict__ y, const float* __restrict__ Wsh,
                  const float* __restrict__ Wg, const float* __restrict__ Wb,
                  unsigned short* __restrict__ w1, unsigned short* __restrict__ w23) {
  const int N1 = BATCH * 27 * 64 * 32;   // 442368
  const int N2 = BATCH * 27 * 64 * 64;   // 884736
  int idx = blockIdx.x * 256 + threadIdx.x;
  if (idx < N1) {
    int ci = idx & 31;
    int m = (idx >> 5) & 63;
    int tap = (idx >> 11) % 27;
    int b = idx / (27 << 11);
    int cls = y[b];
    w1[idx] = f2bf(Wsh[((size_t)((cls * 64 + m) * 32 + ci)) * 27 + tap]);
  } else if (idx < N1 + N2) {
    int j = idx - N1;
    int ci = j & 63;
    int m = (j >> 6) & 63;
    int tap = (j >> 12) % 27;
    int b = j / (27 << 12);
    int cls = y[b];
    float v = (m < 32) ? Wg[((size_t)((cls * 32 + m) * 64 + ci)) * 27 + tap]
                       : Wb[((size_t)((cls * 32 + (m - 32)) * 64 + ci)) * 27 + tap];
    w23[j] = f2bf(v);
  }
}

// ---------------------------------------------------------------- conv1 ----
// actv = relu(conv3x3x3(x; 32->64)), output channels-last bf16.
// Fully-unrolled tap loop: LDS addresses become base + immediate offset.
// Depth-2 register prefetch of weight A-fragments (~2 tap bodies of cover).
__global__ __launch_bounds__(256, 3)
void conv1_kernel(const unsigned short* __restrict__ xcl,
                  const unsigned short* __restrict__ w1,
                  const int* __restrict__ y, const float* __restrict__ bsh,
                  unsigned short* __restrict__ actv) {
  const int d0 = (blockIdx.y / 12) * 4;
  const int h0 = (blockIdx.y % 12) * 4;
  const int w0 = blockIdx.x * 16;
  const int b = blockIdx.z;

  __shared__ unsigned short lds[648 * 40];   // 648 voxels * 80 B = 51840 B

  const int tid = threadIdx.x;
  const size_t xbase = (size_t)b * V3 * CIN;
  for (int i = tid; i < 648 * 4; i += 256) {
    const int v = i >> 2, pp = i & 3;
    const int ld_ = v / 108;
    const int r = v - ld_ * 108;
    const int lh = r / 18;
    const int lw = r - lh * 18;
    const int d = d0 + ld_ - 1, h = h0 + lh - 1, w = w0 + lw - 1;
    uint4 val = make_uint4(0u, 0u, 0u, 0u);
    if ((unsigned)d < 48u && (unsigned)h < 48u && (unsigned)w < 48u)
      val = *reinterpret_cast<const uint4*>(
          &xcl[xbase + ((size_t)((d * 48 + h) * 48 + w)) * CIN + pp * 8]);
    *reinterpret_cast<uint4*>(&lds[v * 40 + pp * 8]) = val;
  }
  __syncthreads();

  const int wave = tid >> 6, lane = tid & 63;
  const int q = lane >> 4, n = lane & 15;

  f32x4 acc[4][4];
#pragma unroll
  for (int g = 0; g < 4; ++g)
#pragma unroll
    for (int mt = 0; mt < 4; ++mt) acc[g][mt] = (f32x4){0.f, 0.f, 0.f, 0.f};

  const unsigned short* wb = w1 + (size_t)b * 27 * 64 * 32 + ((size_t)n) * 32 + q * 8;
  // row layout: [tap][cout][cin]; lane (q,n) reads cout = mt*16+n, cin q*8..q*8+7
  // offset for (tap, mt): (tap*64 + mt*16)*32 ushorts

  bf16x8 areg[2][4];
#pragma unroll
  for (int p = 0; p < 2; ++p)
#pragma unroll
    for (int mt = 0; mt < 4; ++mt)
      areg[p][mt] = *reinterpret_cast<const bf16x8*>(&wb[(p * 64 + mt * 16) * 32]);

  const int vbase = (wave * 6 * 18 + n) * 40 + q * 8;   // ushort units

#pragma unroll
  for (int tap = 0; tap < 27; ++tap) {
    const int dz = tap / 9, dy = (tap / 3) % 3, dx = tap % 3;
    bf16x8 a[4];
#pragma unroll
    for (int mt = 0; mt < 4; ++mt) a[mt] = areg[tap & 1][mt];
    if (tap + 2 < 27) {
#pragma unroll
      for (int mt = 0; mt < 4; ++mt)
        areg[tap & 1][mt] =
            *reinterpret_cast<const bf16x8*>(&wb[((tap + 2) * 64 + mt * 16) * 32]);
    }
    bf16x8 bf[4];
#pragma unroll
    for (int g = 0; g < 4; ++g)
      bf[g] = *reinterpret_cast<const bf16x8*>(
          &lds[vbase + ((dz * 6 + g + dy) * 18 + dx) * 40]);
#pragma unroll
    for (int g = 0; g < 4; ++g)
#pragma unroll
      for (int mt = 0; mt < 4; ++mt)
        acc[g][mt] = __builtin_amdgcn_mfma_f32_16x16x32_bf16(a[mt], bf[g], acc[g][mt], 0, 0, 0);
  }

  const int cls = y[b];
  const int od = d0 + wave, ow = w0 + n;
#pragma unroll
  for (int g = 0; g < 4; ++g) {
    const int oh = h0 + g;
    const size_t vg = (size_t)(od * 48 + oh) * 48 + ow;
#pragma unroll
    for (int mt = 0; mt < 4; ++mt) {
      const int c0 = mt * 16 + q * 4;
      ushort4 pk;
      pk.x = f2bf(fmaxf(acc[g][mt][0] + bsh[cls * 64 + c0 + 0], 0.f));
      pk.y = f2bf(fmaxf(acc[g][mt][1] + bsh[cls * 64 + c0 + 1], 0.f));
      pk.z = f2bf(fmaxf(acc[g][mt][2] + bsh[cls * 64 + c0 + 2], 0.f));
      pk.w = f2bf(fmaxf(acc[g][mt][3] + bsh[cls * 64 + c0 + 3], 0.f));
      *reinterpret_cast<ushort4*>(&actv[((size_t)b * V3 + vg) * NHID + c0]) = pk;
    }
  }
}

// ---------------------------------------------------------------- conv2 ----
__global__ __launch_bounds__(256, 3)
void conv2_kernel(const unsigned short* __restrict__ actv,
                  const unsigned short* __restrict__ w23,
                  const int* __restrict__ y, const float* __restrict__ bgm,
                  const float* __restrict__ bbt, const float* __restrict__ x,
                  const float* __restrict__ mu, const float* __restrict__ rstd,
                  float* __restrict__ out) {
  const int d0 = (blockIdx.y / 12) * 4;
  const int h0 = (blockIdx.y % 12) * 4;
  const int w0 = blockIdx.x * 16;
  const int b = blockIdx.z;

  __shared__ unsigned short lds[648 * 40];

  const int tid = threadIdx.x;
  const int wave = tid >> 6, lane = tid & 63;
  const int q = lane >> 4, n = lane & 15;

  f32x4 acc[4][4];
#pragma unroll
  for (int g = 0; g < 4; ++g)
#pragma unroll
    for (int mt = 0; mt < 4; ++mt) acc[g][mt] = (f32x4){0.f, 0.f, 0.f, 0.f};

  const size_t abase = (size_t)b * V3 * NHID;
  const int vbase = (wave * 6 * 18 + n) * 40 + q * 8;   // ushort units

#pragma unroll
  for (int kc = 0; kc < 2; ++kc) {
    if (kc) __syncthreads();   // protect LDS reuse across passes
    for (int i = tid; i < 648 * 4; i += 256) {
      const int v = i >> 2, pp = i & 3;
      const int ld_ = v / 108;
      const int r = v - ld_ * 108;
      const int lh = r / 18;
      const int lw = r - lh * 18;
      const int d = d0 + ld_ - 1, h = h0 + lh - 1, w = w0 + lw - 1;
      uint4 val = make_uint4(0u, 0u, 0u, 0u);
      if ((unsigned)d < 48u && (unsigned)h < 48u && (unsigned)w < 48u)
        val = *reinterpret_cast<const uint4*>(
            &actv[abase + ((size_t)((d * 48 + h) * 48 + w)) * NHID + kc * 32 + pp * 8]);
      *reinterpret_cast<uint4*>(&lds[v * 40 + pp * 8]) = val;
    }
    __syncthreads();

    // row layout: [tap][cout(64)][cin(64)]; lane reads cout mt*16+n, cin kc*32+q*8..
    const unsigned short* wb =
        w23 + (size_t)b * 27 * 64 * 64 + (size_t)n * 64 + kc * 32 + q * 8;

    bf16x8 areg[2][4];
#pragma unroll
    for (int p = 0; p < 2; ++p)
#pragma unroll
      for (int mt = 0; mt < 4; ++mt)
        areg[p][mt] = *reinterpret_cast<const bf16x8*>(&wb[(p * 64 + mt * 16) * 64]);

#pragma unroll
    for (int tap = 0; tap < 27; ++tap) {
      const int dz = tap / 9, dy = (tap / 3) % 3, dx = tap % 3;
      bf16x8 a[4];
#pragma unroll
      for (int mt = 0; mt < 4; ++mt) a[mt] = areg[tap & 1][mt];
      if (tap + 2 < 27) {
#pragma unroll
        for (int mt = 0; mt < 4; ++mt)
          areg[tap & 1][mt] =
              *reinterpret_cast<const bf16x8*>(&wb[((tap + 2) * 64 + mt * 16) * 64]);
      }
      bf16x8 bf[4];
#pragma unroll
      for (int g = 0; g < 4; ++g)
        bf[g] = *reinterpret_cast<const bf16x8*>(
            &lds[vbase + ((dz * 6 + g + dy) * 18 + dx) * 40]);
#pragma unroll
      for (int g = 0; g < 4; ++g)
#pragma unroll
        for (int mt = 0; mt < 4; ++mt)
          acc[g][mt] = __builtin_amdgcn_mfma_f32_16x16x32_bf16(a[mt], bf[g], acc[g][mt], 0, 0, 0);
    }
  }

  const int cls = y[b];
  const int od = d0 + wave, ow = w0 + n;
#pragma unroll
  for (int g = 0; g < 4; ++g) {
    const int oh = h0 + g;
    const size_t vg = (size_t)(od * 48 + oh) * 48 + ow;
#pragma unroll
    for (int mt = 0; mt < 2; ++mt) {
#pragma unroll
      for (int r = 0; r < 4; ++r) {
        const int c = mt * 16 + q * 4 + r;
        const float gamma = acc[g][mt][r] + bgm[cls * 32 + c];
        const float beta = acc[g][mt + 2][r] + bbt[cls * 32 + c];
        const size_t xi = (size_t)(b * 32 + c) * V3 + vg;
        const float xn = (x[xi] - mu[b * 32 + c]) * rstd[b * 32 + c];
        out[xi] = xn * (1.f + gamma) + beta;
      }
    }
  }
}

// ------------------------------------------------------------------ launch -
extern "C" void kernel_launch(void* const* d_in, const int* in_sizes, int n_in,
                              void* d_out, int out_size, void* d_ws, size_t ws_size,
                              hipStream_t stream) {
  const float* x = (const float*)d_in[0];
  const int* y = (const int*)d_in[1];
  const float* Wsh = (const float*)d_in[2];
  const float* bsh = (const float*)d_in[3];
  const float* Wg = (const float*)d_in[4];
  const float* bg = (const float*)d_in[5];
  const float* Wb = (const float*)d_in[6];
  const float* bb = (const float*)d_in[7];
  float* out = (float*)d_out;

  char* ws = (char*)d_ws;
  unsigned short* xcl  = (unsigned short*)(ws + 0);           // 56,623,104
  unsigned short* actv = (unsigned short*)(ws + 56623104);    // 113,246,208
  unsigned short* w1   = (unsigned short*)(ws + 169869312);   // 884,736
  unsigned short* w23  = (unsigned short*)(ws + 170754048);   // 1,769,472
  float* mu   = (float*)(ws + 172523520);                     // 1024
  float* rstd = (float*)(ws + 172524544);                     // 1024

  stats_kernel<<<256, 256, 0, stream>>>(x, mu, rstd);
  repack_kernel<<<BATCH * 48 * 48, 256, 0, stream>>>(x, xcl);
  wprep_kernel<<<(BATCH * 27 * 64 * 32 + BATCH * 27 * 64 * 64 + 255) / 256, 256, 0, stream>>>(
      y, Wsh, Wg, Wb, w1, w23);

  dim3 grid(3, 144, BATCH);
  conv1_kernel<<<grid, 256, 0, stream>>>(xcl, w1, y, bsh, actv);
  conv2_kernel<<<grid, 256, 0, stream>>>(actv, w23, y, bg, bb, x, mu, rstd, out);
}

// Round 3
// 640.038 us; speedup vs baseline: 1.4453x; 1.4453x over previous
//
#include <hip/hip_runtime.h>
#include <stdint.h>

#define V3 (48*48*48)   // 110592 voxels per channel
#define BATCH 8

typedef __bf16 bf16x8 __attribute__((ext_vector_type(8)));
typedef float  f32x4  __attribute__((ext_vector_type(4)));

__device__ __forceinline__ unsigned short f2bf(float f) {
  uint32_t u = __float_as_uint(f);
  u += 0x7fffu + ((u >> 16) & 1u);   // round-to-nearest-even
  return (unsigned short)(u >> 16);
}

// async 16B global->LDS; LDS dest = wave-uniform base + lane*16
#define GLDS16(gp, lp)                                                         \
  __builtin_amdgcn_global_load_lds(                                            \
      (const __attribute__((address_space(1))) void*)(gp),                     \
      (__attribute__((address_space(3))) void*)(lp), 16, 0, 0)

// ---------------------------------------------------------------- stats ----
// one block per (b,c): mu, rstd over 48^3; block 0 also zeroes the zero page
__global__ __launch_bounds__(256)
void stats_kernel(const float* __restrict__ x, float* __restrict__ mu,
                  float* __restrict__ rstd, float4* __restrict__ zpage) {
  if (blockIdx.x == 0 && threadIdx.x < 64) {
    float4 z; z.x = 0.f; z.y = 0.f; z.z = 0.f; z.w = 0.f;
    zpage[threadIdx.x] = z;
  }
  const int bc = blockIdx.x;  // 0..255
  const float4* p = reinterpret_cast<const float4*>(x + (size_t)bc * V3);
  float s = 0.f, s2 = 0.f;
  for (int i = threadIdx.x; i < V3 / 4; i += 256) {
    float4 v = p[i];
    s  += (v.x + v.y) + (v.z + v.w);
    s2 += (v.x * v.x + v.y * v.y) + (v.z * v.z + v.w * v.w);
  }
  for (int o = 32; o; o >>= 1) { s += __shfl_down(s, o); s2 += __shfl_down(s2, o); }
  __shared__ float red[8];
  const int wave = threadIdx.x >> 6, lane = threadIdx.x & 63;
  if (lane == 0) { red[wave] = s; red[4 + wave] = s2; }
  __syncthreads();
  if (threadIdx.x == 0) {
    float S1 = red[0] + red[1] + red[2] + red[3];
    float S2 = red[4] + red[5] + red[6] + red[7];
    float m = S1 / (float)V3;
    float var = S2 / (float)V3 - m * m;
    mu[bc] = m;
    rstd[bc] = rsqrtf(var + 1e-5f);
  }
}

// --------------------------------------------------------------- repack ----
// x [b][c][d][h][w] fp32 -> xcl [b][d][h][w][c] bf16 (channels-last)
__global__ __launch_bounds__(256)
void repack_kernel(const float* __restrict__ x, unsigned short* __restrict__ xcl) {
  const int bid = blockIdx.x;            // B*48*48 blocks, one (b,d,h) row each
  const int h = bid % 48;
  const int d = (bid / 48) % 48;
  const int b = bid / (48 * 48);
  __shared__ float tile[32][48];
  const float* src = x + (size_t)b * 32 * V3 + (size_t)(d * 48 + h) * 48;
  for (int i = threadIdx.x; i < 32 * 48; i += 256) {
    int c = i / 48, w = i - c * 48;
    tile[c][w] = src[(size_t)c * V3 + w];
  }
  __syncthreads();
  const int i = threadIdx.x;
  if (i < 48 * 4) {
    const int w = i >> 2, pp = i & 3;
    alignas(16) unsigned short pk[8];
#pragma unroll
    for (int j = 0; j < 8; ++j) pk[j] = f2bf(tile[pp * 8 + j][w]);
    *reinterpret_cast<uint4*>(
        &xcl[((size_t)b * V3 + (size_t)(d * 48 + h) * 48 + w) * 32 + pp * 8]) =
        *reinterpret_cast<const uint4*>(pk);
  }
}

// ---------------------------------------------------------------- wprep ----
// Fragment-ordered weights so each wave's A-frag fetch is one coalesced 1KB load.
// w1 : [b][tap(27)][mt(4)][lane(64)][8]   lane=(q*16+n) -> cout=mt*16+n, cin=q*8+j
// w23: [b][kc(2)][tap(27)][mt(4)][lane(64)][8]  cout rows 0-31 gamma, 32-63 beta
__global__ __launch_bounds__(256)
void wprep_kernel(const int* __restrict__ y, const float* __restrict__ Wsh,
                  const float* __restrict__ Wg, const float* __restrict__ Wb,
                  unsigned short* __restrict__ w1, unsigned short* __restrict__ w23) {
  const int N1 = BATCH * 27 * 4 * 64 * 8;       // 442368
  const int N2 = BATCH * 2 * 27 * 4 * 64 * 8;   // 884736
  int idx = blockIdx.x * 256 + threadIdx.x;
  if (idx < N1) {
    const int j = idx & 7;
    const int lane = (idx >> 3) & 63;
    const int mt = (idx >> 9) & 3;
    const int tap = (idx >> 11) % 27;
    const int b = idx / (27 << 11);
    const int q = lane >> 4, n = lane & 15;
    const int cout = mt * 16 + n, cin = q * 8 + j;
    const int cls = y[b];
    w1[idx] = f2bf(Wsh[((size_t)((cls * 64 + cout) * 32 + cin)) * 27 + tap]);
  } else if (idx < N1 + N2) {
    const int t = idx - N1;
    const int b = t / 110592;
    const int r1 = t - b * 110592;
    const int kc = r1 / 55296;
    const int r2 = r1 - kc * 55296;
    const int tap = r2 >> 11;
    const int r3 = r2 & 2047;
    const int mt = r3 >> 9;
    const int lane = (r3 >> 3) & 63;
    const int j = r3 & 7;
    const int q = lane >> 4, n = lane & 15;
    const int cout = mt * 16 + n, cin = kc * 32 + q * 8 + j;
    const int cls = y[b];
    float v = (cout < 32) ? Wg[((size_t)((cls * 32 + cout) * 64 + cin)) * 27 + tap]
                          : Wb[((size_t)((cls * 32 + (cout - 32)) * 64 + cin)) * 27 + tap];
    w23[t] = f2bf(v);
  }
}

// ---------------------------------------------------------------- conv1 ----
// actv = relu(conv3x3x3(x; 32->64)), channels-last bf16 out.
// Tile 4d x 6h x 16w; halo 6x8x18 = 864 voxels; LDS SoA [pp(4)][864][16B] = 55296B.
// Staging via global_load_lds(16B); OOB lanes read a zeroed page (SAME pad = 0).
__global__ __launch_bounds__(256, 2)
void conv1_kernel(const unsigned short* __restrict__ xcl,
                  const unsigned short* __restrict__ w1,
                  const int* __restrict__ y, const float* __restrict__ bsh,
                  unsigned short* __restrict__ actv,
                  const float4* __restrict__ zpage) {
  const int d0 = (blockIdx.y >> 3) * 4;
  const int h0 = (blockIdx.y & 7) * 6;
  const int w0 = blockIdx.x * 16;
  const int b = blockIdx.z;

  __shared__ unsigned short lds[4 * 864 * 8];   // 55296 B

  const int tid = threadIdx.x;
  const int lane = tid & 63;
  const int wave = tid >> 6;

  const unsigned short* xb = xcl + (size_t)b * V3 * 32;
  for (int i = tid; i < 3456; i += 256) {
    const int pp = i / 864;
    const int v = i - pp * 864;
    const int ld_ = v / 144;
    const int r = v - ld_ * 144;
    const int lh = r / 18;
    const int lw = r - lh * 18;
    const int d = d0 + ld_ - 1, h = h0 + lh - 1, w = w0 + lw - 1;
    const bool ok = (unsigned)d < 48u && (unsigned)h < 48u && (unsigned)w < 48u;
    const void* gp =
        ok ? (const void*)(xb + ((size_t)((d * 48 + h) * 48 + w)) * 32 + pp * 8)
           : (const void*)((const char*)zpage + lane * 16);
    GLDS16(gp, &lds[(size_t)(i - lane) * 8]);
  }
  __syncthreads();

  const int q = lane >> 4, n = lane & 15;

  f32x4 acc[6][4];
#pragma unroll
  for (int g = 0; g < 6; ++g)
#pragma unroll
    for (int mt = 0; mt < 4; ++mt) acc[g][mt] = (f32x4){0.f, 0.f, 0.f, 0.f};

  const unsigned short* wb = w1 + (size_t)b * 55296 + lane * 8;

  bf16x8 acur[4], anxt[4];
#pragma unroll
  for (int mt = 0; mt < 4; ++mt)
    acur[mt] = *reinterpret_cast<const bf16x8*>(&wb[mt * 512]);

  const int vb0 = q * 864 + wave * 144 + n;   // chunk index base

  for (int tap = 0; tap < 27; ++tap) {
    if (tap < 26) {
#pragma unroll
      for (int mt = 0; mt < 4; ++mt)
        anxt[mt] = *reinterpret_cast<const bf16x8*>(&wb[((tap + 1) * 4 + mt) * 512]);
    }
    const int dz = tap / 9, rr = tap - dz * 9, dy = rr / 3, dx = rr - dy * 3;
    const int vb = vb0 + dz * 144 + dy * 18 + dx;
    bf16x8 bf[6];
#pragma unroll
    for (int g = 0; g < 6; ++g)
      bf[g] = *reinterpret_cast<const bf16x8*>(&lds[(size_t)(vb + g * 18) * 8]);
#pragma unroll
    for (int g = 0; g < 6; ++g)
#pragma unroll
      for (int mt = 0; mt < 4; ++mt)
        acc[g][mt] = __builtin_amdgcn_mfma_f32_16x16x32_bf16(acur[mt], bf[g], acc[g][mt], 0, 0, 0);
#pragma unroll
    for (int mt = 0; mt < 4; ++mt) acur[mt] = anxt[mt];
  }

  const int cls = y[b];
  const int od = d0 + wave, ow = w0 + n;
#pragma unroll
  for (int g = 0; g < 6; ++g) {
    const int oh = h0 + g;
    const size_t vg = (size_t)(od * 48 + oh) * 48 + ow;
#pragma unroll
    for (int mt = 0; mt < 4; ++mt) {
      const int c0 = mt * 16 + q * 4;
      ushort4 pk;
      pk.x = f2bf(fmaxf(acc[g][mt][0] + bsh[cls * 64 + c0 + 0], 0.f));
      pk.y = f2bf(fmaxf(acc[g][mt][1] + bsh[cls * 64 + c0 + 1], 0.f));
      pk.z = f2bf(fmaxf(acc[g][mt][2] + bsh[cls * 64 + c0 + 2], 0.f));
      pk.w = f2bf(fmaxf(acc[g][mt][3] + bsh[cls * 64 + c0 + 3], 0.f));
      *reinterpret_cast<ushort4*>(&actv[((size_t)b * V3 + vg) * 64 + c0]) = pk;
    }
  }
}

// ---------------------------------------------------------------- conv2 ----
// gamma/beta = conv3x3x3(actv; 64->32 each, stacked 64 couts), fused epilogue
// out = (x-mu)*rstd*(1+gamma) + beta.  Same tile/layout as conv1; 2 kc passes.
__global__ __launch_bounds__(256, 2)
void conv2_kernel(const unsigned short* __restrict__ actv,
                  const unsigned short* __restrict__ w23,
                  const int* __restrict__ y, const float* __restrict__ bgm,
                  const float* __restrict__ bbt, const float* __restrict__ x,
                  const float* __restrict__ mu, const float* __restrict__ rstd,
                  float* __restrict__ out, const float4* __restrict__ zpage) {
  const int d0 = (blockIdx.y >> 3) * 4;
  const int h0 = (blockIdx.y & 7) * 6;
  const int w0 = blockIdx.x * 16;
  const int b = blockIdx.z;

  __shared__ unsigned short lds[4 * 864 * 8];   // 55296 B

  const int tid = threadIdx.x;
  const int lane = tid & 63;
  const int wave = tid >> 6;
  const int q = lane >> 4, n = lane & 15;

  f32x4 acc[6][4];
#pragma unroll
  for (int g = 0; g < 6; ++g)
#pragma unroll
    for (int mt = 0; mt < 4; ++mt) acc[g][mt] = (f32x4){0.f, 0.f, 0.f, 0.f};

  const unsigned short* ab = actv + (size_t)b * V3 * 64;
  const int vb0 = q * 864 + wave * 144 + n;

  for (int kc = 0; kc < 2; ++kc) {
    if (kc) __syncthreads();   // LDS reuse across passes
    for (int i = tid; i < 3456; i += 256) {
      const int pp = i / 864;
      const int v = i - pp * 864;
      const int ld_ = v / 144;
      const int r = v - ld_ * 144;
      const int lh = r / 18;
      const int lw = r - lh * 18;
      const int d = d0 + ld_ - 1, h = h0 + lh - 1, w = w0 + lw - 1;
      const bool ok = (unsigned)d < 48u && (unsigned)h < 48u && (unsigned)w < 48u;
      const void* gp =
          ok ? (const void*)(ab + ((size_t)((d * 48 + h) * 48 + w)) * 64 + kc * 32 + pp * 8)
             : (const void*)((const char*)zpage + lane * 16);
      GLDS16(gp, &lds[(size_t)(i - lane) * 8]);
    }
    __syncthreads();

    const unsigned short* wb = w23 + (size_t)b * 110592 + (size_t)kc * 55296 + lane * 8;

    bf16x8 acur[4], anxt[4];
#pragma unroll
    for (int mt = 0; mt < 4; ++mt)
      acur[mt] = *reinterpret_cast<const bf16x8*>(&wb[mt * 512]);

    for (int tap = 0; tap < 27; ++tap) {
      if (tap < 26) {
#pragma unroll
        for (int mt = 0; mt < 4; ++mt)
          anxt[mt] = *reinterpret_cast<const bf16x8*>(&wb[((tap + 1) * 4 + mt) * 512]);
      }
      const int dz = tap / 9, rr = tap - dz * 9, dy = rr / 3, dx = rr - dy * 3;
      const int vb = vb0 + dz * 144 + dy * 18 + dx;
      bf16x8 bf[6];
#pragma unroll
      for (int g = 0; g < 6; ++g)
        bf[g] = *reinterpret_cast<const bf16x8*>(&lds[(size_t)(vb + g * 18) * 8]);
#pragma unroll
      for (int g = 0; g < 6; ++g)
#pragma unroll
        for (int mt = 0; mt < 4; ++mt)
          acc[g][mt] = __builtin_amdgcn_mfma_f32_16x16x32_bf16(acur[mt], bf[g], acc[g][mt], 0, 0, 0);
#pragma unroll
      for (int mt = 0; mt < 4; ++mt) acur[mt] = anxt[mt];
    }
  }

  const int cls = y[b];
  const int od = d0 + wave, ow = w0 + n;
#pragma unroll
  for (int g = 0; g < 6; ++g) {
    const int oh = h0 + g;
    const size_t vg = (size_t)(od * 48 + oh) * 48 + ow;
#pragma unroll
    for (int mt = 0; mt < 2; ++mt) {
#pragma unroll
      for (int r = 0; r < 4; ++r) {
        const int c = mt * 16 + q * 4 + r;
        const float gamma = acc[g][mt][r] + bgm[cls * 32 + c];
        const float beta = acc[g][mt + 2][r] + bbt[cls * 32 + c];
        const size_t xi = (size_t)(b * 32 + c) * V3 + vg;
        const float xn = (x[xi] - mu[b * 32 + c]) * rstd[b * 32 + c];
        out[xi] = xn * (1.f + gamma) + beta;
      }
    }
  }
}

// ------------------------------------------------------------------ launch -
extern "C" void kernel_launch(void* const* d_in, const int* in_sizes, int n_in,
                              void* d_out, int out_size, void* d_ws, size_t ws_size,
                              hipStream_t stream) {
  const float* x = (const float*)d_in[0];
  const int* y = (const int*)d_in[1];
  const float* Wsh = (const float*)d_in[2];
  const float* bsh = (const float*)d_in[3];
  const float* Wg = (const float*)d_in[4];
  const float* bg = (const float*)d_in[5];
  const float* Wb = (const float*)d_in[6];
  const float* bb = (const float*)d_in[7];
  float* out = (float*)d_out;

  char* ws = (char*)d_ws;
  unsigned short* xcl  = (unsigned short*)(ws + 0);           // 56,623,104 B
  unsigned short* actv = (unsigned short*)(ws + 56623104);    // 113,246,208 B
  unsigned short* w1   = (unsigned short*)(ws + 169869312);   //    884,736 B
  unsigned short* w23  = (unsigned short*)(ws + 170754048);   //  1,769,472 B
  float* mu    = (float*)(ws + 172523520);                    //      1,024 B
  float* rstd  = (float*)(ws + 172524544);                    //      1,024 B
  float4* zpg  = (float4*)(ws + 172525568);                   //      1,024 B

  stats_kernel<<<256, 256, 0, stream>>>(x, mu, rstd, zpg);
  repack_kernel<<<BATCH * 48 * 48, 256, 0, stream>>>(x, xcl);
  wprep_kernel<<<(BATCH * 27 * 4 * 64 * 8 * 3 + 255) / 256, 256, 0, stream>>>(
      y, Wsh, Wg, Wb, w1, w23);

  dim3 grid(3, 96, BATCH);   // w:3, (d:12 x h:8):96, b:8
  conv1_kernel<<<grid, 256, 0, stream>>>(xcl, w1, y, bsh, actv, zpg);
  conv2_kernel<<<grid, 256, 0, stream>>>(actv, w23, y, bg, bb, x, mu, rstd, out, zpg);
}